// Round 8
// baseline (464.265 us; speedup 1.0000x reference)
//
#include <hip/hip_runtime.h>

#define B_SZ 1024
#define T_SZ 128
#define HID 512
#define LAB 100

// ---- d_ws layout (byte offsets) ----
#define OFF_X     0u          // int[262144]              1 MB
#define OFF_WH    1048576u    // ushort[262144]           512 KB
#define OFF_LEN   1572864u    // ushort[96000]  (bf16 len_emb)
#define OFF_IPD   1764864u    // ushort[16384]  (bf16 ipd_emb)
#define OFF_FC2   1797632u    // ushort[51200]
#define OFF_X2H   1900032u    // ushort[65536]
#define OFF_FC2B  2031104u    // float[100] (+pad)
#define OFF_FC1   2031616u    // ushort[16384]  (bf16 fc1)
#define OFF_WEFF  2064384u    // ushort[65536]  bf16 Weff[512][128]
#define OFF_BEFF  2195456u    // float[512]
#define OFF_ELEN  2197504u    // float[256][512] = 512 KB
#define OFF_EIPD  2721792u    // float[256][512] = 512 KB
#define WS_NEED   3246080u

typedef __attribute__((ext_vector_type(8))) short short8;
typedef __attribute__((ext_vector_type(4))) float float4v;
typedef __attribute__((ext_vector_type(4))) unsigned short us4;
typedef __attribute__((ext_vector_type(8))) __bf16 bf8_t;
typedef unsigned long long ull;

__device__ __attribute__((aligned(16))) unsigned char g_blob[WS_NEED]; // fallback only

__device__ __forceinline__ float bf2f(unsigned short u) {
    union { unsigned int i; float f; } z; z.i = ((unsigned int)u) << 16; return z.f;
}
__device__ __forceinline__ unsigned short f2bf(float f) {
    union { float f; unsigned int i; } z; z.f = f;
    unsigned int r = z.i + 0x7FFFu + ((z.i >> 16) & 1u);
    return (unsigned short)(r >> 16);
}
__device__ __forceinline__ float4v mfma16(short8 a, short8 b, float4v c) {
    return __builtin_amdgcn_mfma_f32_16x16x32_bf16(
        __builtin_bit_cast(bf8_t, a), __builtin_bit_cast(bf8_t, b), c, 0, 0, 0);
}

// ---------------------------------------------------------------------------
// Merged conversion kernel (r7-proven-neutral): blocks 0..255 convert x,
// blocks 256..1279 convert weights/embeddings to bf16 (incl. fc1).
// ---------------------------------------------------------------------------
__global__ void conv_kernel(const int* __restrict__ xi, int* __restrict__ xo,
                            const float* __restrict__ len_e, const float* __restrict__ ipd_e,
                            const float* __restrict__ h2h, const float* __restrict__ fc2,
                            const float* __restrict__ x2h, const float* __restrict__ fc2b,
                            const float* __restrict__ fc1,
                            unsigned short* __restrict__ o_len, unsigned short* __restrict__ o_ipd,
                            unsigned short* __restrict__ o_wh, unsigned short* __restrict__ o_fc2,
                            unsigned short* __restrict__ o_x2h, float* __restrict__ o_fc2b,
                            unsigned short* __restrict__ o_fc1) {
    if (blockIdx.x < 256) {
        __shared__ int is64;
        if (threadIdx.x == 0) {
            int nz = 0;
            for (int j = 1; j < 64; j += 2) nz |= xi[j];
            is64 = (nz == 0) ? 1 : 0;
        }
        __syncthreads();
        const int n = B_SZ * T_SZ * 2;
        const int i64 = is64;
        for (int i = blockIdx.x * blockDim.x + threadIdx.x; i < n; i += 256 * blockDim.x) {
            int v = i64 ? xi[2 * i] : xi[i];
            v = v < 0 ? 0 : (v > 255 ? 255 : v);
            xo[i] = v;
        }
        return;
    }
    const int N0 = 96000, N1 = 16384, N2 = 262144, N3 = 51200, N4 = 65536, N5 = 100, N6 = 16384;
    const int total = N0 + N1 + N2 + N3 + N4 + N5 + N6;
    for (int i = (blockIdx.x - 256) * blockDim.x + threadIdx.x; i < total; i += 1024 * blockDim.x) {
        int j = i;
        if (j < N0) { o_len[j] = f2bf(len_e[j]); continue; }
        j -= N0;
        if (j < N1) { o_ipd[j] = f2bf(ipd_e[j]); continue; }
        j -= N1;
        if (j < N2) { o_wh[j] = f2bf(h2h[j]); continue; }
        j -= N2;
        if (j < N3) { o_fc2[j] = f2bf(fc2[j]); continue; }
        j -= N3;
        if (j < N4) { o_x2h[j] = f2bf(x2h[j]); continue; }
        j -= N4;
        if (j < N5) { o_fc2b[j] = fc2b[j]; continue; }
        j -= N5;
        o_fc1[j] = f2bf(fc1[j]);
    }
}

// ---------------------------------------------------------------------------
// prep1: Weff[n][k] = sum_j x2h[n][j] * fc1[j][k]   (bf16 in, f32 acc, bf16 out)
//        beff[n]    = x2h_b[n] + h2h_b[n] + sum_j x2h[n][j]*fc1_b[j]  (pure f32)
// 64 blocks x 256 threads (4 waves); wave -> one 16x16 tile of Weff (256 tiles).
// fc1^T staged in 32 KB static LDS per block. MFMA addressing mirrors the
// proven xin GEMM fragment pattern (A-row=mcol, k=q*8; out[Brow=mcol][Arow=q*4+r]).
// ---------------------------------------------------------------------------
__launch_bounds__(256)
__global__ void prep1_kernel(const unsigned short* __restrict__ w_x2h,
                             const unsigned short* __restrict__ w_fc1,
                             const float* __restrict__ x2h_f,
                             const float* __restrict__ fc1b_f,
                             const float* __restrict__ x2hb_f,
                             const float* __restrict__ h2hb_f,
                             unsigned short* __restrict__ w_weff,
                             float* __restrict__ w_beff) {
    __shared__ unsigned short fc1T[128 * 128];
    const int tid = threadIdx.x;
    // stage fc1^T: fc1T[k][j] = fc1[j][k]
    for (int it = 0; it < 64; it++) {
        int idx = it * 256 + tid;          // j*128 + k
        int j = idx >> 7, k = idx & 127;
        fc1T[k * 128 + j] = w_fc1[idx];
    }
    // beff on global threads 0..511 (f32 exact)
    int tg = blockIdx.x * 256 + tid;
    if (tg < 512) {
        float s = x2hb_f[tg] + h2hb_f[tg];
        const float* xr = x2h_f + tg * 128;
        for (int j = 0; j < 128; j++) s += xr[j] * fc1b_f[j];
        w_beff[tg] = s;
    }
    __syncthreads();

    const int wv = tid >> 6, ln = tid & 63;
    const int mcol = ln & 15, q = ln >> 4;
    const int id = blockIdx.x * 4 + wv;    // 0..255
    const int nt = id >> 3, kt = id & 7;   // n-tile (32), k-tile (8)
    float4v acc = {0.f, 0.f, 0.f, 0.f};
#pragma unroll
    for (int j = 0; j < 4; j++) {
        short8 fa = *(const short8*)(w_x2h + (nt * 16 + mcol) * 128 + j * 32 + q * 8);
        short8 bf = *(const short8*)&fc1T[(kt * 16 + mcol) * 128 + j * 32 + q * 8];
        acc = mfma16(fa, bf, acc);
    }
    // out[Brow=k_local=mcol][Arow=n_local=q*4+r] -> Weff[(nt*16+q*4+r)][kt*16+mcol]
#pragma unroll
    for (int r = 0; r < 4; r++)
        w_weff[(nt * 16 + q * 4 + r) * 128 + kt * 16 + mcol] = f2bf(acc[r]);
}

// ---------------------------------------------------------------------------
// prep2: E_len[v][n] = sum_{k<64}  len[v][k]   * Weff[n][k]
//        E_ipd[v][n] = sum_{k>=64} ipd[v][k-64]* Weff[n][k] + beff[n]
// f32 output tables (256x512 each). 256 blocks x 256 threads; wave -> one
// 16(v) x 16(n) tile; 1024 tiles total (512 per table). K=64 -> 2 MFMAs.
// ---------------------------------------------------------------------------
__launch_bounds__(256)
__global__ void prep2_kernel(const unsigned short* __restrict__ w_weff,
                             const float* __restrict__ w_beff,
                             const unsigned short* __restrict__ w_len,
                             const unsigned short* __restrict__ w_ipd,
                             float* __restrict__ w_elen,
                             float* __restrict__ w_eipd) {
    const int tid = threadIdx.x;
    const int wv = tid >> 6, ln = tid & 63;
    const int mcol = ln & 15, q = ln >> 4;
    const int id = blockIdx.x * 4 + wv;    // 0..1023
    const int isI = id >> 9;               // 0: E_len, 1: E_ipd
    const int id2 = id & 511;
    const int vt = id2 >> 5, nt = id2 & 31;
    const unsigned short* emb = isI ? w_ipd : w_len;
    float4v acc = {0.f, 0.f, 0.f, 0.f};
#pragma unroll
    for (int kt = 0; kt < 2; kt++) {
        short8 fa = *(const short8*)(w_weff + (nt * 16 + mcol) * 128 + isI * 64 + kt * 32 + q * 8);
        short8 bf = *(const short8*)(emb + (vt * 16 + mcol) * 64 + kt * 32 + q * 8);
        acc = mfma16(fa, bf, acc);
    }
    const int n0 = nt * 16 + q * 4;
    if (isI) {
        float4v b4 = *(const float4v*)&w_beff[n0];
        acc[0] += b4[0]; acc[1] += b4[1]; acc[2] += b4[2]; acc[3] += b4[3];
    }
    float* dst = isI ? w_eipd : w_elen;
    *(float4v*)&dst[(vt * 16 + mcol) * 512 + n0] = acc;   // E[v][n], n contiguous
}

// ---------------------------------------------------------------------------
// RNN v5: proven v3 structure (64 blocks x 512 threads, 2 waves/SIMD;
// Wh kt0..11 in 192 regs, kt12..15 in 128 KB swizzled LDS; h dbuf; fast tanh;
// strength-reduced addressing). xin REPLACED by table gather-add:
//   acc_init[b,t] = E_len[x0[b,t]] + E_ipd[x1[b,t]]   (f32 tables, L2-resident)
// prefetched one step ahead into epre[4] (f32x4 = +8 VGPRs vs xq; ~254/256).
// No xin buffer, no producer blocks, no sync protocol.
// ---------------------------------------------------------------------------
__launch_bounds__(512, 2)
__global__ void rnn_kernel(const unsigned short* __restrict__ w_wh,
                           const int* __restrict__ w_x,
                           const float* __restrict__ w_elen,
                           const float* __restrict__ w_eipd,
                           const unsigned short* __restrict__ w_fc2,
                           const float* __restrict__ w_fc2b,
                           float* __restrict__ out) {
    extern __shared__ unsigned short sm2[];
    unsigned short* sA = sm2;            // Wh k 384..511: 65536 ushorts (128 KB)
    unsigned short* sH = sm2 + 65536;    // h dbuf: 2 x 8192 ushorts (32 KB)

    const int tid  = threadIdx.x;
    const int wv   = tid >> 6;           // 0..7
    const int ln   = tid & 63;
    const int mcol = ln & 15;            // batch col within block
    const int q    = ln >> 4;
    const int g    = blockIdx.x;
    const int b0   = g * 16;
    const int n0   = wv * 64;            // wave owns hidden rows n0..n0+63

    // ---- stage Wh kt 12..15 into LDS (swizzled) ----
    for (int it = 0; it < 16; it++) {
        int chunk = it * 512 + tid;          // 0..8191
        int r = chunk >> 4, c = chunk & 15;
        uint4 v = *(const uint4*)(w_wh + r * 512 + 384 + c * 8);
        *(uint4*)&sA[r * 128 + ((c ^ (r & 15)) & 15) * 8] = v;
    }
    // ---- zero h buffer 0 ----
    {
        uint4 z = {0, 0, 0, 0};
        *(uint4*)&sH[tid * 8] = z;
        *(uint4*)&sH[(512 + tid) * 8] = z;
    }
    // ---- Wh kt 0..11 into registers: 48 frags = 192 regs ----
    short8 whr[4][12];
#pragma unroll
    for (int nt = 0; nt < 4; nt++)
#pragma unroll
        for (int kt = 0; kt < 12; kt++)
            whr[nt][kt] = *(const short8*)(w_wh + (n0 + nt * 16 + mcol) * 512 + kt * 32 + q * 8);

    // ---- strength-reduced swizzle offsets (ushort units) ----
    const int qlo = (q ^ (mcol & 3)) * 8;
    int ej[4];
#pragma unroll
    for (int j = 0; j < 4; j++)
        ej[j] = ((j * 4) ^ (mcol & 12)) * 8;
    const int base_b = mcol * 512 + qlo;          // h-read base
    const int fbase  = (n0 + mcol) * 128 + qlo;   // sA-read base
    int hw_off[4];
#pragma unroll
    for (int nt = 0; nt < 4; nt++) {
        int n = n0 + nt * 16 + q * 4;
        hw_off[nt] = mcol * 512 + (((n >> 3) ^ mcol) & 63) * 8 + (n & 7);
    }

    // ---- gather-add prefetch (t=0): epre = E_len[x0] + E_ipd[x1] ----
    const int xrow = (b0 + mcol) * 256;   // w_x row base for this batch
    const int ecol = n0 + q * 4;
    float4v epre[4];
    {
        int2 i01 = *(const int2*)&w_x[xrow];
        const float* eL = w_elen + i01.x * 512 + ecol;
        const float* eI = w_eipd + i01.y * 512 + ecol;
#pragma unroll
        for (int nt = 0; nt < 4; nt++) {
            float4v a = *(const float4v*)(eL + nt * 16);
            float4v b = *(const float4v*)(eI + nt * 16);
            epre[nt][0] = a[0] + b[0]; epre[nt][1] = a[1] + b[1];
            epre[nt][2] = a[2] + b[2]; epre[nt][3] = a[3] + b[3];
        }
    }

    __syncthreads();

    for (int t = 0; t < T_SZ; t++) {
        const unsigned short* hRd = sH + ((t & 1) << 13);
        unsigned short* hWr = sH + (((t + 1) & 1) << 13);

        // ---- acc init from prefetched gather-add ----
        float4v acc[4];
#pragma unroll
        for (int nt = 0; nt < 4; nt++) acc[nt] = epre[nt];

        // ---- prefetch next step's gather-add (hidden under MFMA phase) ----
        if (t + 1 < T_SZ) {
            int2 i01 = *(const int2*)&w_x[xrow + (t + 1) * 2];
            const float* eL = w_elen + i01.x * 512 + ecol;
            const float* eI = w_eipd + i01.y * 512 + ecol;
#pragma unroll
            for (int nt = 0; nt < 4; nt++) {
                float4v a = *(const float4v*)(eL + nt * 16);
                float4v b = *(const float4v*)(eI + nt * 16);
                epre[nt][0] = a[0] + b[0]; epre[nt][1] = a[1] + b[1];
                epre[nt][2] = a[2] + b[2]; epre[nt][3] = a[3] + b[3];
            }
        }

        // ---- Wh MFMAs: kt 0..11 from regs ----
#pragma unroll
        for (int kt = 0; kt < 12; kt++) {
            short8 bh = *(const short8*)&hRd[base_b + ej[kt & 3] + (kt >> 2) * 128];
#pragma unroll
            for (int nt = 0; nt < 4; nt++)
                acc[nt] = mfma16(whr[nt][kt], bh, acc[nt]);
        }
        // ---- kt 12..15 from LDS ----
#pragma unroll
        for (int j = 0; j < 4; j++) {
            short8 bh = *(const short8*)&hRd[base_b + ej[j] + 384];
#pragma unroll
            for (int nt = 0; nt < 4; nt++) {
                short8 fa = *(const short8*)&sA[fbase + nt * 2048 + ej[j]];
                acc[nt] = mfma16(fa, bh, acc[nt]);
            }
        }

        // ---- fast tanh -> bf16, write h(t+1) into other buffer ----
#pragma unroll
        for (int nt = 0; nt < 4; nt++) {
            unsigned short o[4];
#pragma unroll
            for (int r = 0; r < 4; r++) {
                float e  = __expf(2.0f * acc[nt][r]);
                float th = 1.0f - 2.0f * __builtin_amdgcn_rcpf(e + 1.0f);
                o[r] = f2bf(th);
            }
            us4 v4 = { o[0], o[1], o[2], o[3] };
            *(us4*)&hWr[hw_off[nt]] = v4;
        }
        __syncthreads();   // h(t+1) visible to all waves before next step
    }

    // final h is in buffer 0 (T_SZ even)
    unsigned short* hF = sH;

    // ---- fc2 epilogue: waves 0..6 cover 112 >= 100 labels ----
    if (wv < 7) {
        int lA = wv * 16 + mcol; if (lA > 99) lA = 99;
        float4v a2 = {0.f, 0.f, 0.f, 0.f};
#pragma unroll
        for (int kt = 0; kt < 16; kt++) {
            short8 fa = *(const short8*)(w_fc2 + lA * 512 + kt * 32 + q * 8);
            short8 bh = *(const short8*)&hF[base_b + ej[kt & 3] + (kt >> 2) * 128];
            a2 = mfma16(fa, bh, a2);
        }
#pragma unroll
        for (int r = 0; r < 4; r++) {
            int l = wv * 16 + q * 4 + r;
            if (l < 100) out[(b0 + mcol) * 100 + l] = a2[r] + w_fc2b[l];
        }
    }
}

extern "C" void kernel_launch(void* const* d_in, const int* in_sizes, int n_in,
                              void* d_out, int out_size, void* d_ws, size_t ws_size,
                              hipStream_t stream) {
    unsigned char* base = (unsigned char*)d_ws;
    if (ws_size < (size_t)WS_NEED) {
        void* p = nullptr;
        hipGetSymbolAddress(&p, HIP_SYMBOL(g_blob));
        base = (unsigned char*)p;
    }
    int*            w_x    = (int*)(base + OFF_X);
    unsigned short* w_wh   = (unsigned short*)(base + OFF_WH);
    unsigned short* w_len  = (unsigned short*)(base + OFF_LEN);
    unsigned short* w_ipd  = (unsigned short*)(base + OFF_IPD);
    unsigned short* w_fc2  = (unsigned short*)(base + OFF_FC2);
    unsigned short* w_x2h  = (unsigned short*)(base + OFF_X2H);
    float*          w_fc2b = (float*)(base + OFF_FC2B);
    unsigned short* w_fc1  = (unsigned short*)(base + OFF_FC1);
    unsigned short* w_weff = (unsigned short*)(base + OFF_WEFF);
    float*          w_beff = (float*)(base + OFF_BEFF);
    float*          w_elen = (float*)(base + OFF_ELEN);
    float*          w_eipd = (float*)(base + OFF_EIPD);

    static bool attr_set = false;
    if (!attr_set) {
        hipFuncSetAttribute((const void*)rnn_kernel,
                            hipFuncAttributeMaxDynamicSharedMemorySize, 163840);
        attr_set = true;
    }

    conv_kernel<<<1280, 256, 0, stream>>>(
        (const int*)d_in[0], w_x,
        (const float*)d_in[1], (const float*)d_in[2], (const float*)d_in[7],
        (const float*)d_in[9], (const float*)d_in[5], (const float*)d_in[10],
        (const float*)d_in[3],
        w_len, w_ipd, w_wh, w_fc2, w_x2h, w_fc2b, w_fc1);
    prep1_kernel<<<64, 256, 0, stream>>>(
        w_x2h, w_fc1,
        (const float*)d_in[5], (const float*)d_in[4],
        (const float*)d_in[6], (const float*)d_in[8],
        w_weff, w_beff);
    prep2_kernel<<<256, 256, 0, stream>>>(
        w_weff, w_beff, w_len, w_ipd, w_elen, w_eipd);
    rnn_kernel<<<64, 512, 163840, stream>>>(
        w_wh, w_x, w_elen, w_eipd, w_fc2, w_fc2b, (float*)d_out);
}

// Round 9
// 424.351 us; speedup vs baseline: 1.0941x; 1.0941x over previous
//
#include <hip/hip_runtime.h>

#define B_SZ 1024
#define T_SZ 128
#define HID 512
#define LAB 100

// ---- d_ws layout (byte offsets) ----
#define OFF_X     0u          // int[262144]              1 MB
#define OFF_WH    1048576u    // ushort[262144]           512 KB
#define OFF_LEN   1572864u    // ushort[96000]  (bf16 len_emb)
#define OFF_IPD   1764864u    // ushort[16384]  (bf16 ipd_emb)
#define OFF_FC2   1797632u    // ushort[51200]
#define OFF_X2H   1900032u    // ushort[65536]
#define OFF_FC2B  2031104u    // float[100] (+pad)
#define OFF_FC1   2031616u    // ushort[16384]  (bf16 fc1)
#define OFF_WEFF  2064384u    // ushort[65536]  bf16 Weff[512][128]
#define OFF_BEFF  2195456u    // float[512]
#define OFF_ELEN  2197504u    // float[256][512] = 512 KB
#define OFF_EIPD  2721792u    // float[256][512] = 512 KB
#define WS_NEED   3246080u

typedef __attribute__((ext_vector_type(8))) short short8;
typedef __attribute__((ext_vector_type(4))) float float4v;
typedef __attribute__((ext_vector_type(4))) unsigned short us4;
typedef __attribute__((ext_vector_type(8))) __bf16 bf8_t;
typedef unsigned long long ull;

__device__ __attribute__((aligned(16))) unsigned char g_blob[WS_NEED]; // fallback only

__device__ __forceinline__ float bf2f(unsigned short u) {
    union { unsigned int i; float f; } z; z.i = ((unsigned int)u) << 16; return z.f;
}
__device__ __forceinline__ unsigned short f2bf(float f) {
    union { float f; unsigned int i; } z; z.f = f;
    unsigned int r = z.i + 0x7FFFu + ((z.i >> 16) & 1u);
    return (unsigned short)(r >> 16);
}
__device__ __forceinline__ float4v mfma16(short8 a, short8 b, float4v c) {
    return __builtin_amdgcn_mfma_f32_16x16x32_bf16(
        __builtin_bit_cast(bf8_t, a), __builtin_bit_cast(bf8_t, b), c, 0, 0, 0);
}

// ---------------------------------------------------------------------------
// Merged conversion kernel: blocks 0..255 convert x, blocks 256..1279 convert
// weights/embeddings to bf16 (incl. fc1).
// ---------------------------------------------------------------------------
__global__ void conv_kernel(const int* __restrict__ xi, int* __restrict__ xo,
                            const float* __restrict__ len_e, const float* __restrict__ ipd_e,
                            const float* __restrict__ h2h, const float* __restrict__ fc2,
                            const float* __restrict__ x2h, const float* __restrict__ fc2b,
                            const float* __restrict__ fc1,
                            unsigned short* __restrict__ o_len, unsigned short* __restrict__ o_ipd,
                            unsigned short* __restrict__ o_wh, unsigned short* __restrict__ o_fc2,
                            unsigned short* __restrict__ o_x2h, float* __restrict__ o_fc2b,
                            unsigned short* __restrict__ o_fc1) {
    if (blockIdx.x < 256) {
        __shared__ int is64;
        if (threadIdx.x == 0) {
            int nz = 0;
            for (int j = 1; j < 64; j += 2) nz |= xi[j];
            is64 = (nz == 0) ? 1 : 0;
        }
        __syncthreads();
        const int n = B_SZ * T_SZ * 2;
        const int i64 = is64;
        for (int i = blockIdx.x * blockDim.x + threadIdx.x; i < n; i += 256 * blockDim.x) {
            int v = i64 ? xi[2 * i] : xi[i];
            v = v < 0 ? 0 : (v > 255 ? 255 : v);
            xo[i] = v;
        }
        return;
    }
    const int N0 = 96000, N1 = 16384, N2 = 262144, N3 = 51200, N4 = 65536, N5 = 100, N6 = 16384;
    const int total = N0 + N1 + N2 + N3 + N4 + N5 + N6;
    for (int i = (blockIdx.x - 256) * blockDim.x + threadIdx.x; i < total; i += 1024 * blockDim.x) {
        int j = i;
        if (j < N0) { o_len[j] = f2bf(len_e[j]); continue; }
        j -= N0;
        if (j < N1) { o_ipd[j] = f2bf(ipd_e[j]); continue; }
        j -= N1;
        if (j < N2) { o_wh[j] = f2bf(h2h[j]); continue; }
        j -= N2;
        if (j < N3) { o_fc2[j] = f2bf(fc2[j]); continue; }
        j -= N3;
        if (j < N4) { o_x2h[j] = f2bf(x2h[j]); continue; }
        j -= N4;
        if (j < N5) { o_fc2b[j] = fc2b[j]; continue; }
        j -= N5;
        o_fc1[j] = f2bf(fc1[j]);
    }
}

// ---------------------------------------------------------------------------
// prep1: Weff[n][k] = sum_j x2h[n][j] * fc1[j][k]; beff[n] = x2hb+h2hb+x2h.fc1b
// (proven correct in r8 — absmax improved to 0.0022). beff loop vectorized.
// ---------------------------------------------------------------------------
__launch_bounds__(256)
__global__ void prep1_kernel(const unsigned short* __restrict__ w_x2h,
                             const unsigned short* __restrict__ w_fc1,
                             const float* __restrict__ x2h_f,
                             const float* __restrict__ fc1b_f,
                             const float* __restrict__ x2hb_f,
                             const float* __restrict__ h2hb_f,
                             unsigned short* __restrict__ w_weff,
                             float* __restrict__ w_beff) {
    __shared__ unsigned short fc1T[128 * 128];
    const int tid = threadIdx.x;
    // stage fc1^T: fc1T[k][j] = fc1[j][k]
    for (int it = 0; it < 64; it++) {
        int idx = it * 256 + tid;          // j*128 + k
        int j = idx >> 7, k = idx & 127;
        fc1T[k * 128 + j] = w_fc1[idx];
    }
    // beff on global threads 0..511 (f32 exact, float4 loads)
    int tg = blockIdx.x * 256 + tid;
    if (tg < 512) {
        float s = x2hb_f[tg] + h2hb_f[tg];
        const float4v* xr = (const float4v*)(x2h_f + tg * 128);
        const float4v* bb = (const float4v*)fc1b_f;
        for (int j = 0; j < 32; j++) {
            float4v a = xr[j], b = bb[j];
            s += a[0] * b[0] + a[1] * b[1] + a[2] * b[2] + a[3] * b[3];
        }
        w_beff[tg] = s;
    }
    __syncthreads();

    const int wv = tid >> 6, ln = tid & 63;
    const int mcol = ln & 15, q = ln >> 4;
    const int id = blockIdx.x * 4 + wv;    // 0..255
    const int nt = id >> 3, kt = id & 7;   // n-tile (32), k-tile (8)
    float4v acc = {0.f, 0.f, 0.f, 0.f};
#pragma unroll
    for (int j = 0; j < 4; j++) {
        short8 fa = *(const short8*)(w_x2h + (nt * 16 + mcol) * 128 + j * 32 + q * 8);
        short8 bf = *(const short8*)&fc1T[(kt * 16 + mcol) * 128 + j * 32 + q * 8];
        acc = mfma16(fa, bf, acc);
    }
#pragma unroll
    for (int r = 0; r < 4; r++)
        w_weff[(nt * 16 + q * 4 + r) * 128 + kt * 16 + mcol] = f2bf(acc[r]);
}

// ---------------------------------------------------------------------------
// prep2: E_len[v][n] = len[v]·Weff[n][:64]; E_ipd[v][n] = ipd[v]·Weff[n][64:]+beff
// f32 tables 256x512 each (proven r8).
// ---------------------------------------------------------------------------
__launch_bounds__(256)
__global__ void prep2_kernel(const unsigned short* __restrict__ w_weff,
                             const float* __restrict__ w_beff,
                             const unsigned short* __restrict__ w_len,
                             const unsigned short* __restrict__ w_ipd,
                             float* __restrict__ w_elen,
                             float* __restrict__ w_eipd) {
    const int tid = threadIdx.x;
    const int wv = tid >> 6, ln = tid & 63;
    const int mcol = ln & 15, q = ln >> 4;
    const int id = blockIdx.x * 4 + wv;    // 0..1023
    const int isI = id >> 9;               // 0: E_len, 1: E_ipd
    const int id2 = id & 511;
    const int vt = id2 >> 5, nt = id2 & 31;
    const unsigned short* emb = isI ? w_ipd : w_len;
    float4v acc = {0.f, 0.f, 0.f, 0.f};
#pragma unroll
    for (int kt = 0; kt < 2; kt++) {
        short8 fa = *(const short8*)(w_weff + (nt * 16 + mcol) * 128 + isI * 64 + kt * 32 + q * 8);
        short8 bf = *(const short8*)(emb + (vt * 16 + mcol) * 64 + kt * 32 + q * 8);
        acc = mfma16(fa, bf, acc);
    }
    const int n0 = nt * 16 + q * 4;
    if (isI) {
        float4v b4 = *(const float4v*)&w_beff[n0];
        acc[0] += b4[0]; acc[1] += b4[1]; acc[2] += b4[2]; acc[3] += b4[3];
    }
    float* dst = isI ? w_eipd : w_elen;
    *(float4v*)&dst[(vt * 16 + mcol) * 512 + n0] = acc;
}

// ---------------------------------------------------------------------------
// RNN v6: v3 structure + table gather SOFTWARE-PIPELINED (r8 lesson: the
// idx->table dependent chain + add-at-issue-site exposed ~2300 cyc/step).
// Pipeline: idxP holds x[t+1] (loaded 1 step early); at step-t top:
//   acc = tA+tB (loads from t-1, landed)  -> waitcnt free
//   issue 8 table loads for t+1 (idxP resident, NO chain)
//   issue idx load for t+2
// All loads drain under the MFMA+tanh phase, like the proven xin prefetch.
// Registers: tA/tB 32 + idx 2 (vs epre 16) ~ +18 vs r8; watch WRITE_SIZE.
// ---------------------------------------------------------------------------
__launch_bounds__(512, 2)
__global__ void rnn_kernel(const unsigned short* __restrict__ w_wh,
                           const int* __restrict__ w_x,
                           const float* __restrict__ w_elen,
                           const float* __restrict__ w_eipd,
                           const unsigned short* __restrict__ w_fc2,
                           const float* __restrict__ w_fc2b,
                           float* __restrict__ out) {
    extern __shared__ unsigned short sm2[];
    unsigned short* sA = sm2;            // Wh k 384..511: 65536 ushorts (128 KB)
    unsigned short* sH = sm2 + 65536;    // h dbuf: 2 x 8192 ushorts (32 KB)

    const int tid  = threadIdx.x;
    const int wv   = tid >> 6;           // 0..7
    const int ln   = tid & 63;
    const int mcol = ln & 15;            // batch col within block
    const int q    = ln >> 4;
    const int g    = blockIdx.x;
    const int b0   = g * 16;
    const int n0   = wv * 64;            // wave owns hidden rows n0..n0+63

    // ---- stage Wh kt 12..15 into LDS (swizzled) ----
    for (int it = 0; it < 16; it++) {
        int chunk = it * 512 + tid;          // 0..8191
        int r = chunk >> 4, c = chunk & 15;
        uint4 v = *(const uint4*)(w_wh + r * 512 + 384 + c * 8);
        *(uint4*)&sA[r * 128 + ((c ^ (r & 15)) & 15) * 8] = v;
    }
    // ---- zero h buffer 0 ----
    {
        uint4 z = {0, 0, 0, 0};
        *(uint4*)&sH[tid * 8] = z;
        *(uint4*)&sH[(512 + tid) * 8] = z;
    }
    // ---- Wh kt 0..11 into registers: 48 frags = 192 regs ----
    short8 whr[4][12];
#pragma unroll
    for (int nt = 0; nt < 4; nt++)
#pragma unroll
        for (int kt = 0; kt < 12; kt++)
            whr[nt][kt] = *(const short8*)(w_wh + (n0 + nt * 16 + mcol) * 512 + kt * 32 + q * 8);

    // ---- strength-reduced swizzle offsets (ushort units) ----
    const int qlo = (q ^ (mcol & 3)) * 8;
    int ej[4];
#pragma unroll
    for (int j = 0; j < 4; j++)
        ej[j] = ((j * 4) ^ (mcol & 12)) * 8;
    const int base_b = mcol * 512 + qlo;          // h-read base
    const int fbase  = (n0 + mcol) * 128 + qlo;   // sA-read base
    int hw_off[4];
#pragma unroll
    for (int nt = 0; nt < 4; nt++) {
        int n = n0 + nt * 16 + q * 4;
        hw_off[nt] = mcol * 512 + (((n >> 3) ^ mcol) & 63) * 8 + (n & 7);
    }

    // ---- gather pipeline prologue ----
    const int xrow = (b0 + mcol) * 256;   // w_x row base for this batch col
    const int ecol = n0 + q * 4;
    float4v tA[4], tB[4];
    {
        int2 i0 = *(const int2*)&w_x[xrow];               // x[t=0]
        const float* eL = w_elen + i0.x * 512 + ecol;
        const float* eI = w_eipd + i0.y * 512 + ecol;
#pragma unroll
        for (int nt = 0; nt < 4; nt++) {
            tA[nt] = *(const float4v*)(eL + nt * 16);
            tB[nt] = *(const float4v*)(eI + nt * 16);
        }
    }
    int2 idxP = *(const int2*)&w_x[xrow + 2];             // x[t=1]

    __syncthreads();

    for (int t = 0; t < T_SZ; t++) {
        const unsigned short* hRd = sH + ((t & 1) << 13);
        unsigned short* hWr = sH + (((t + 1) & 1) << 13);

        // ---- acc init: add at CONSUME site (loads from step t-1, landed) ----
        float4v acc[4];
#pragma unroll
        for (int nt = 0; nt < 4; nt++) {
            acc[nt][0] = tA[nt][0] + tB[nt][0];
            acc[nt][1] = tA[nt][1] + tB[nt][1];
            acc[nt][2] = tA[nt][2] + tB[nt][2];
            acc[nt][3] = tA[nt][3] + tB[nt][3];
        }
        // ---- issue next-step table loads (idxP resident -> no chain) ----
        if (t + 1 < T_SZ) {
            const float* eL = w_elen + idxP.x * 512 + ecol;
            const float* eI = w_eipd + idxP.y * 512 + ecol;
#pragma unroll
            for (int nt = 0; nt < 4; nt++) {
                tA[nt] = *(const float4v*)(eL + nt * 16);
                tB[nt] = *(const float4v*)(eI + nt * 16);
            }
            if (t + 2 < T_SZ)
                idxP = *(const int2*)&w_x[xrow + (t + 2) * 2];  // 1 step of slack
        }

        // ---- Wh MFMAs: kt 0..11 from regs ----
#pragma unroll
        for (int kt = 0; kt < 12; kt++) {
            short8 bh = *(const short8*)&hRd[base_b + ej[kt & 3] + (kt >> 2) * 128];
#pragma unroll
            for (int nt = 0; nt < 4; nt++)
                acc[nt] = mfma16(whr[nt][kt], bh, acc[nt]);
        }
        // ---- kt 12..15 from LDS ----
#pragma unroll
        for (int j = 0; j < 4; j++) {
            short8 bh = *(const short8*)&hRd[base_b + ej[j] + 384];
#pragma unroll
            for (int nt = 0; nt < 4; nt++) {
                short8 fa = *(const short8*)&sA[fbase + nt * 2048 + ej[j]];
                acc[nt] = mfma16(fa, bh, acc[nt]);
            }
        }

        // ---- fast tanh -> bf16, write h(t+1) into other buffer ----
#pragma unroll
        for (int nt = 0; nt < 4; nt++) {
            unsigned short o[4];
#pragma unroll
            for (int r = 0; r < 4; r++) {
                float e  = __expf(2.0f * acc[nt][r]);
                float th = 1.0f - 2.0f * __builtin_amdgcn_rcpf(e + 1.0f);
                o[r] = f2bf(th);
            }
            us4 v4 = { o[0], o[1], o[2], o[3] };
            *(us4*)&hWr[hw_off[nt]] = v4;
        }
        __syncthreads();   // h(t+1) visible to all waves before next step
    }

    // final h is in buffer 0 (T_SZ even)
    unsigned short* hF = sH;

    // ---- fc2 epilogue: waves 0..6 cover 112 >= 100 labels ----
    if (wv < 7) {
        int lA = wv * 16 + mcol; if (lA > 99) lA = 99;
        float4v a2 = {0.f, 0.f, 0.f, 0.f};
#pragma unroll
        for (int kt = 0; kt < 16; kt++) {
            short8 fa = *(const short8*)(w_fc2 + lA * 512 + kt * 32 + q * 8);
            short8 bh = *(const short8*)&hF[base_b + ej[kt & 3] + (kt >> 2) * 128];
            a2 = mfma16(fa, bh, a2);
        }
#pragma unroll
        for (int r = 0; r < 4; r++) {
            int l = wv * 16 + q * 4 + r;
            if (l < 100) out[(b0 + mcol) * 100 + l] = a2[r] + w_fc2b[l];
        }
    }
}

extern "C" void kernel_launch(void* const* d_in, const int* in_sizes, int n_in,
                              void* d_out, int out_size, void* d_ws, size_t ws_size,
                              hipStream_t stream) {
    unsigned char* base = (unsigned char*)d_ws;
    if (ws_size < (size_t)WS_NEED) {
        void* p = nullptr;
        hipGetSymbolAddress(&p, HIP_SYMBOL(g_blob));
        base = (unsigned char*)p;
    }
    int*            w_x    = (int*)(base + OFF_X);
    unsigned short* w_wh   = (unsigned short*)(base + OFF_WH);
    unsigned short* w_len  = (unsigned short*)(base + OFF_LEN);
    unsigned short* w_ipd  = (unsigned short*)(base + OFF_IPD);
    unsigned short* w_fc2  = (unsigned short*)(base + OFF_FC2);
    unsigned short* w_x2h  = (unsigned short*)(base + OFF_X2H);
    float*          w_fc2b = (float*)(base + OFF_FC2B);
    unsigned short* w_fc1  = (unsigned short*)(base + OFF_FC1);
    unsigned short* w_weff = (unsigned short*)(base + OFF_WEFF);
    float*          w_beff = (float*)(base + OFF_BEFF);
    float*          w_elen = (float*)(base + OFF_ELEN);
    float*          w_eipd = (float*)(base + OFF_EIPD);

    static bool attr_set = false;
    if (!attr_set) {
        hipFuncSetAttribute((const void*)rnn_kernel,
                            hipFuncAttributeMaxDynamicSharedMemorySize, 163840);
        attr_set = true;
    }

    conv_kernel<<<1280, 256, 0, stream>>>(
        (const int*)d_in[0], w_x,
        (const float*)d_in[1], (const float*)d_in[2], (const float*)d_in[7],
        (const float*)d_in[9], (const float*)d_in[5], (const float*)d_in[10],
        (const float*)d_in[3],
        w_len, w_ipd, w_wh, w_fc2, w_x2h, w_fc2b, w_fc1);
    prep1_kernel<<<64, 256, 0, stream>>>(
        w_x2h, w_fc1,
        (const float*)d_in[5], (const float*)d_in[4],
        (const float*)d_in[6], (const float*)d_in[8],
        w_weff, w_beff);
    prep2_kernel<<<256, 256, 0, stream>>>(
        w_weff, w_beff, w_len, w_ipd, w_elen, w_eipd);
    rnn_kernel<<<64, 512, 163840, stream>>>(
        w_wh, w_x, w_elen, w_eipd, w_fc2, w_fc2b, (float*)d_out);
}

// Round 10
// 407.399 us; speedup vs baseline: 1.1396x; 1.0416x over previous
//
#include <hip/hip_runtime.h>

#define B_SZ 1024
#define T_SZ 128
#define HID 512
#define LAB 100

// ---- d_ws layout (byte offsets) ----
#define OFF_XC    0u          // uchar2 t-major [128][1024][2] = 256 KB
#define OFF_WH    262144u     // ushort[262144] bf16 Wh        = 512 KB
#define OFF_FC2   786432u     // ushort[51200]  bf16 fc2
#define OFF_FC2B  888832u     // float[100] (+pad)
#define OFF_WEFFT 889344u     // float[128][512] Weff^T        = 256 KB
#define OFF_BEFF  1151488u    // float[512]
#define OFF_ELEN  1153536u    // ushort[256][512] bf16         = 256 KB
#define OFF_EIPD  1415680u    // ushort[256][512] bf16         = 256 KB
#define WS_NEED   1677824u

typedef __attribute__((ext_vector_type(8))) short short8;
typedef __attribute__((ext_vector_type(4))) float float4v;
typedef __attribute__((ext_vector_type(4))) unsigned short us4;
typedef __attribute__((ext_vector_type(8))) __bf16 bf8_t;
typedef unsigned long long ull;

__device__ __attribute__((aligned(16))) unsigned char g_blob[WS_NEED]; // fallback only

__device__ __forceinline__ float bf2f(unsigned short u) {
    union { unsigned int i; float f; } z; z.i = ((unsigned int)u) << 16; return z.f;
}
__device__ __forceinline__ unsigned short f2bf(float f) {
    union { float f; unsigned int i; } z; z.f = f;
    unsigned int r = z.i + 0x7FFFu + ((z.i >> 16) & 1u);
    return (unsigned short)(r >> 16);
}
__device__ __forceinline__ float4v mfma16(short8 a, short8 b, float4v c) {
    return __builtin_amdgcn_mfma_f32_16x16x32_bf16(
        __builtin_bit_cast(bf8_t, a), __builtin_bit_cast(bf8_t, b), c, 0, 0, 0);
}

// ---------------------------------------------------------------------------
// K1 (834 blocks x 256): role-split by blockIdx (uniform per block):
//  [0,256)   : x -> uchar2 t-major  xc[t][b] = (x0,x1), clamped to [0,255]
//  [256,320) : Weff^T[k][n] = sum_j x2h_f32[n][j] * fc1_f32[j][k]  (64 blocks,
//              4 outputs/thread along n -> coalesced f32 writes)
//  [320,322) : beff[n] = x2hb+h2hb+sum_j x2h[n][j]*fc1b[j]  (512 threads)
//  [322,834) : bf16 conversions: Wh, fc2; fc2b copy (512 blocks)
// All roles independent; one launch replaces conv+prep1.
// ---------------------------------------------------------------------------
__global__ void k1_kernel(const int* __restrict__ xi, unsigned char* __restrict__ xc,
                          const float* __restrict__ fc1_f, const float* __restrict__ fc1b_f,
                          const float* __restrict__ x2h_f, const float* __restrict__ x2hb_f,
                          const float* __restrict__ h2hb_f,
                          const float* __restrict__ h2h_f, const float* __restrict__ fc2_f,
                          const float* __restrict__ fc2b_f,
                          float* __restrict__ wefft, float* __restrict__ beff,
                          unsigned short* __restrict__ o_wh, unsigned short* __restrict__ o_fc2,
                          float* __restrict__ o_fc2b) {
    const int tid = threadIdx.x;
    if (blockIdx.x < 256) {
        __shared__ int is64;
        if (tid == 0) {
            int nz = 0;
            for (int j = 1; j < 64; j += 2) nz |= xi[j];
            is64 = (nz == 0) ? 1 : 0;
        }
        __syncthreads();
        const int n = B_SZ * T_SZ * 2;
        const int i64 = is64;
        for (int i = blockIdx.x * 256 + tid; i < n; i += 256 * 256) {
            int v = i64 ? xi[2 * i] : xi[i];
            v = v < 0 ? 0 : (v > 255 ? 255 : v);
            int b = i >> 8, r = i & 255, t = r >> 1, c = r & 1;
            xc[t * 2048 + b * 2 + c] = (unsigned char)v;
        }
        return;
    }
    if (blockIdx.x < 320) {
        // Weff^T: o = (blk-256)*1024 + tid*4 -> k = o>>9, n0 = o&511
        int o = (blockIdx.x - 256) * 1024 + tid * 4;
        int k = o >> 9, n0 = o & 511;
        float a0 = 0.f, a1 = 0.f, a2 = 0.f, a3 = 0.f;
#pragma unroll 4
        for (int j = 0; j < 128; j++) {
            float f = fc1_f[j * 128 + k];
            a0 += f * x2h_f[(n0 + 0) * 128 + j];
            a1 += f * x2h_f[(n0 + 1) * 128 + j];
            a2 += f * x2h_f[(n0 + 2) * 128 + j];
            a3 += f * x2h_f[(n0 + 3) * 128 + j];
        }
        float4v v = { a0, a1, a2, a3 };
        *(float4v*)&wefft[k * 512 + n0] = v;
        return;
    }
    if (blockIdx.x < 322) {
        int tg = (blockIdx.x - 320) * 256 + tid;   // 0..511
        float s = x2hb_f[tg] + h2hb_f[tg];
        const float4v* xr = (const float4v*)(x2h_f + tg * 128);
        const float4v* bb = (const float4v*)fc1b_f;
        for (int j = 0; j < 32; j++) {
            float4v a = xr[j], b = bb[j];
            s += a[0] * b[0] + a[1] * b[1] + a[2] * b[2] + a[3] * b[3];
        }
        beff[tg] = s;
        return;
    }
    // conversions: Wh (262144) + fc2 (51200) + fc2b (100)
    const int N2 = 262144, N3 = 51200, N5 = 100;
    const int total = N2 + N3 + N5;
    for (int i = (blockIdx.x - 322) * 256 + tid; i < total; i += 512 * 256) {
        int j = i;
        if (j < N2) { o_wh[j] = f2bf(h2h_f[j]); continue; }
        j -= N2;
        if (j < N3) { o_fc2[j] = f2bf(fc2_f[j]); continue; }
        j -= N3;
        o_fc2b[j] = fc2b_f[j];
    }
}

// ---------------------------------------------------------------------------
// K2 (256 blocks x 256): bf16 tables, single rounding from all-f32 pipeline:
//   E_len[v][n] = sum_{k<64} len_f32[v][k] * Weff^T[k][n]
//   E_ipd[v][n] = sum_{k<64} ipd_f32[v][k] * Weff^T[64+k][n] + beff[n]
// grp = blk*256+tid; tab = grp>>15; v = (grp>>7)&255; n0 = (grp&127)*4.
// Weff^T float4 reads coalesced (n contiguous); emb scalar broadcast.
// ---------------------------------------------------------------------------
__launch_bounds__(256)
__global__ void k2_kernel(const float* __restrict__ wefft, const float* __restrict__ beff,
                          const float* __restrict__ len_f, const float* __restrict__ ipd_f,
                          unsigned short* __restrict__ elen, unsigned short* __restrict__ eipd) {
    int grp = blockIdx.x * 256 + threadIdx.x;      // 0..65535
    int tab = grp >> 15;                           // 0: len, 1: ipd
    int g2  = grp & 32767;
    int v   = g2 >> 7;
    int n0  = (g2 & 127) * 4;
    const float* emb = (tab ? ipd_f : len_f) + v * 64;
    const float* wt  = wefft + tab * 64 * 512 + n0;
    float a0 = 0.f, a1 = 0.f, a2 = 0.f, a3 = 0.f;
#pragma unroll 8
    for (int k = 0; k < 64; k++) {
        float e = emb[k];
        float4v w = *(const float4v*)(wt + k * 512);
        a0 += e * w[0]; a1 += e * w[1]; a2 += e * w[2]; a3 += e * w[3];
    }
    if (tab) {
        float4v b4 = *(const float4v*)&beff[n0];
        a0 += b4[0]; a1 += b4[1]; a2 += b4[2]; a3 += b4[3];
    }
    us4 o = { f2bf(a0), f2bf(a1), f2bf(a2), f2bf(a3) };
    unsigned short* dst = tab ? eipd : elen;
    *(us4*)&dst[v * 512 + n0] = o;
}

// ---------------------------------------------------------------------------
// RNN v7: v3 proven structure. Gather now bf16 tables (halves L1 line
// transactions: 8 dwordx4 -> 8 dwordx2 per thread-step; r9 lesson) with the
// r9 software pipeline (idxP one step ahead; loads issued with resident idx;
// add at consume site). x index read = one 32B broadcast line per wave
// (uchar2 t-major). Registers: whr 192 + acc 16 + tq/ti 16 + addr ~25 ~= 250.
// ---------------------------------------------------------------------------
__launch_bounds__(512, 2)
__global__ void rnn_kernel(const unsigned short* __restrict__ w_wh,
                           const unsigned char* __restrict__ w_xc,
                           const unsigned short* __restrict__ w_elen,
                           const unsigned short* __restrict__ w_eipd,
                           const unsigned short* __restrict__ w_fc2,
                           const float* __restrict__ w_fc2b,
                           float* __restrict__ out) {
    extern __shared__ unsigned short sm2[];
    unsigned short* sA = sm2;            // Wh k 384..511: 65536 ushorts (128 KB)
    unsigned short* sH = sm2 + 65536;    // h dbuf: 2 x 8192 ushorts (32 KB)

    const int tid  = threadIdx.x;
    const int wv   = tid >> 6;           // 0..7
    const int ln   = tid & 63;
    const int mcol = ln & 15;            // batch col within block
    const int q    = ln >> 4;
    const int g    = blockIdx.x;
    const int b0   = g * 16;
    const int n0   = wv * 64;            // wave owns hidden rows n0..n0+63

    // ---- stage Wh kt 12..15 into LDS (swizzled) ----
    for (int it = 0; it < 16; it++) {
        int chunk = it * 512 + tid;          // 0..8191
        int r = chunk >> 4, c = chunk & 15;
        uint4 v = *(const uint4*)(w_wh + r * 512 + 384 + c * 8);
        *(uint4*)&sA[r * 128 + ((c ^ (r & 15)) & 15) * 8] = v;
    }
    // ---- zero h buffer 0 ----
    {
        uint4 z = {0, 0, 0, 0};
        *(uint4*)&sH[tid * 8] = z;
        *(uint4*)&sH[(512 + tid) * 8] = z;
    }
    // ---- Wh kt 0..11 into registers: 48 frags = 192 regs ----
    short8 whr[4][12];
#pragma unroll
    for (int nt = 0; nt < 4; nt++)
#pragma unroll
        for (int kt = 0; kt < 12; kt++)
            whr[nt][kt] = *(const short8*)(w_wh + (n0 + nt * 16 + mcol) * 512 + kt * 32 + q * 8);

    // ---- strength-reduced swizzle offsets (ushort units) ----
    const int qlo = (q ^ (mcol & 3)) * 8;
    int ej[4];
#pragma unroll
    for (int j = 0; j < 4; j++)
        ej[j] = ((j * 4) ^ (mcol & 12)) * 8;
    const int base_b = mcol * 512 + qlo;          // h-read base
    const int fbase  = (n0 + mcol) * 128 + qlo;   // sA-read base
    int hw_off[4];
#pragma unroll
    for (int nt = 0; nt < 4; nt++) {
        int n = n0 + nt * 16 + q * 4;
        hw_off[nt] = mcol * 512 + (((n >> 3) ^ mcol) & 63) * 8 + (n & 7);
    }

    // ---- gather pipeline prologue (bf16 tables, packed uchar2 idx) ----
    const int xb2  = (b0 + mcol) * 2;     // byte offset within a t-slice
    const int ecol = n0 + q * 4;
    us4 tq[4], ti[4];
    {
        unsigned int i0 = *(const unsigned short*)&w_xc[xb2];          // x[t=0]
        const unsigned short* eL = w_elen + (i0 & 255u) * 512 + ecol;
        const unsigned short* eI = w_eipd + (i0 >> 8) * 512 + ecol;
#pragma unroll
        for (int nt = 0; nt < 4; nt++) {
            tq[nt] = *(const us4*)(eL + nt * 16);
            ti[nt] = *(const us4*)(eI + nt * 16);
        }
    }
    unsigned int idxP = *(const unsigned short*)&w_xc[2048 + xb2];     // x[t=1]

    __syncthreads();

    for (int t = 0; t < T_SZ; t++) {
        const unsigned short* hRd = sH + ((t & 1) << 13);
        unsigned short* hWr = sH + (((t + 1) & 1) << 13);

        // ---- acc init: bf16->f32 + add at CONSUME site (loads landed) ----
        float4v acc[4];
#pragma unroll
        for (int nt = 0; nt < 4; nt++) {
            acc[nt][0] = bf2f(tq[nt][0]) + bf2f(ti[nt][0]);
            acc[nt][1] = bf2f(tq[nt][1]) + bf2f(ti[nt][1]);
            acc[nt][2] = bf2f(tq[nt][2]) + bf2f(ti[nt][2]);
            acc[nt][3] = bf2f(tq[nt][3]) + bf2f(ti[nt][3]);
        }
        // ---- issue next-step table loads (idxP resident -> no chain) ----
        if (t + 1 < T_SZ) {
            const unsigned short* eL = w_elen + (idxP & 255u) * 512 + ecol;
            const unsigned short* eI = w_eipd + (idxP >> 8) * 512 + ecol;
#pragma unroll
            for (int nt = 0; nt < 4; nt++) {
                tq[nt] = *(const us4*)(eL + nt * 16);
                ti[nt] = *(const us4*)(eI + nt * 16);
            }
            if (t + 2 < T_SZ)
                idxP = *(const unsigned short*)&w_xc[(t + 2) * 2048 + xb2];
        }

        // ---- Wh MFMAs: kt 0..11 from regs ----
#pragma unroll
        for (int kt = 0; kt < 12; kt++) {
            short8 bh = *(const short8*)&hRd[base_b + ej[kt & 3] + (kt >> 2) * 128];
#pragma unroll
            for (int nt = 0; nt < 4; nt++)
                acc[nt] = mfma16(whr[nt][kt], bh, acc[nt]);
        }
        // ---- kt 12..15 from LDS ----
#pragma unroll
        for (int j = 0; j < 4; j++) {
            short8 bh = *(const short8*)&hRd[base_b + ej[j] + 384];
#pragma unroll
            for (int nt = 0; nt < 4; nt++) {
                short8 fa = *(const short8*)&sA[fbase + nt * 2048 + ej[j]];
                acc[nt] = mfma16(fa, bh, acc[nt]);
            }
        }

        // ---- fast tanh -> bf16, write h(t+1) into other buffer ----
#pragma unroll
        for (int nt = 0; nt < 4; nt++) {
            unsigned short o[4];
#pragma unroll
            for (int r = 0; r < 4; r++) {
                float e  = __expf(2.0f * acc[nt][r]);
                float th = 1.0f - 2.0f * __builtin_amdgcn_rcpf(e + 1.0f);
                o[r] = f2bf(th);
            }
            us4 v4 = { o[0], o[1], o[2], o[3] };
            *(us4*)&hWr[hw_off[nt]] = v4;
        }
        __syncthreads();   // h(t+1) visible to all waves before next step
    }

    // final h is in buffer 0 (T_SZ even)
    unsigned short* hF = sH;

    // ---- fc2 epilogue: waves 0..6 cover 112 >= 100 labels ----
    if (wv < 7) {
        int lA = wv * 16 + mcol; if (lA > 99) lA = 99;
        float4v a2 = {0.f, 0.f, 0.f, 0.f};
#pragma unroll
        for (int kt = 0; kt < 16; kt++) {
            short8 fa = *(const short8*)(w_fc2 + lA * 512 + kt * 32 + q * 8);
            short8 bh = *(const short8*)&hF[base_b + ej[kt & 3] + (kt >> 2) * 128];
            a2 = mfma16(fa, bh, a2);
        }
#pragma unroll
        for (int r = 0; r < 4; r++) {
            int l = wv * 16 + q * 4 + r;
            if (l < 100) out[(b0 + mcol) * 100 + l] = a2[r] + w_fc2b[l];
        }
    }
}

extern "C" void kernel_launch(void* const* d_in, const int* in_sizes, int n_in,
                              void* d_out, int out_size, void* d_ws, size_t ws_size,
                              hipStream_t stream) {
    unsigned char* base = (unsigned char*)d_ws;
    if (ws_size < (size_t)WS_NEED) {
        void* p = nullptr;
        hipGetSymbolAddress(&p, HIP_SYMBOL(g_blob));
        base = (unsigned char*)p;
    }
    unsigned char*  w_xc    = base + OFF_XC;
    unsigned short* w_wh    = (unsigned short*)(base + OFF_WH);
    unsigned short* w_fc2   = (unsigned short*)(base + OFF_FC2);
    float*          w_fc2b  = (float*)(base + OFF_FC2B);
    float*          w_wefft = (float*)(base + OFF_WEFFT);
    float*          w_beff  = (float*)(base + OFF_BEFF);
    unsigned short* w_elen  = (unsigned short*)(base + OFF_ELEN);
    unsigned short* w_eipd  = (unsigned short*)(base + OFF_EIPD);

    static bool attr_set = false;
    if (!attr_set) {
        hipFuncSetAttribute((const void*)rnn_kernel,
                            hipFuncAttributeMaxDynamicSharedMemorySize, 163840);
        attr_set = true;
    }

    k1_kernel<<<834, 256, 0, stream>>>(
        (const int*)d_in[0], w_xc,
        (const float*)d_in[3], (const float*)d_in[4],
        (const float*)d_in[5], (const float*)d_in[6], (const float*)d_in[8],
        (const float*)d_in[7], (const float*)d_in[9], (const float*)d_in[10],
        w_wefft, w_beff, w_wh, w_fc2, w_fc2b);
    k2_kernel<<<256, 256, 0, stream>>>(
        w_wefft, w_beff,
        (const float*)d_in[1], (const float*)d_in[2],
        w_elen, w_eipd);
    rnn_kernel<<<64, 512, 163840, stream>>>(
        w_wh, w_xc, w_elen, w_eipd, w_fc2, w_fc2b, (float*)d_out);
}

// Round 11
// 397.081 us; speedup vs baseline: 1.1692x; 1.0260x over previous
//
#include <hip/hip_runtime.h>

#define B_SZ 1024
#define T_SZ 128
#define HID 512
#define LAB 100

// ---- d_ws layout (byte offsets) ----
#define OFF_XC    0u          // uchar2 t-major [128][1024][2] = 256 KB
#define OFF_WH    262144u     // ushort[262144] bf16 Wh        = 512 KB
#define OFF_FC2   786432u     // ushort[51200]  bf16 fc2
#define OFF_FC2B  888832u     // float[100] (+pad)
#define OFF_WEFFT 889344u     // float[128][512] Weff^T        = 256 KB
#define OFF_BEFF  1151488u    // float[512]
#define OFF_ELEN  1153536u    // ushort[256][512] bf16         = 256 KB
#define OFF_EIPD  1415680u    // ushort[256][512] bf16         = 256 KB
#define WS_NEED   1677824u

typedef __attribute__((ext_vector_type(8))) short short8;
typedef __attribute__((ext_vector_type(4))) float float4v;
typedef __attribute__((ext_vector_type(4))) unsigned short us4;
typedef __attribute__((ext_vector_type(8))) __bf16 bf8_t;
typedef unsigned long long ull;

__device__ __attribute__((aligned(16))) unsigned char g_blob[WS_NEED]; // fallback only

__device__ __forceinline__ float bf2f(unsigned short u) {
    union { unsigned int i; float f; } z; z.i = ((unsigned int)u) << 16; return z.f;
}
__device__ __forceinline__ unsigned short f2bf(float f) {
    union { float f; unsigned int i; } z; z.f = f;
    unsigned int r = z.i + 0x7FFFu + ((z.i >> 16) & 1u);
    return (unsigned short)(r >> 16);
}
__device__ __forceinline__ float4v mfma16(short8 a, short8 b, float4v c) {
    return __builtin_amdgcn_mfma_f32_16x16x32_bf16(
        __builtin_bit_cast(bf8_t, a), __builtin_bit_cast(bf8_t, b), c, 0, 0, 0);
}

// ---------------------------------------------------------------------------
// K1 (66 blocks x 256): the only work that must precede the table build.
//  [0,64) : Weff^T[k][n] = sum_j x2h[n][j]*fc1[j][k]  — COALESCED mapping
//           (r10 lesson: old mapping touched ~256 lines/iter/wave; new one:
//           thread=(n, 4k): x2h[n*128+j] is a wave broadcast (2 lines/iter),
//           fc1[j*128+k0] a shared float4 row (8 lines/iter). The uncoalesced
//           stores are one-time (4 scalars/thread).)
//  [64,66): beff[n] = x2hb[n]+h2hb[n]+sum_j x2h[n][j]*fc1b[j]  (f32 exact)
// ---------------------------------------------------------------------------
__launch_bounds__(256)
__global__ void k1_kernel(const float* __restrict__ fc1_f, const float* __restrict__ fc1b_f,
                          const float* __restrict__ x2h_f, const float* __restrict__ x2hb_f,
                          const float* __restrict__ h2hb_f,
                          float* __restrict__ wefft, float* __restrict__ beff) {
    const int tid = threadIdx.x;
    if (blockIdx.x < 64) {
        int gid = blockIdx.x * 256 + tid;     // 0..16383
        int n  = gid >> 5;                    // 0..511 (32 threads per n)
        int k0 = (gid & 31) * 4;              // 0,4,...,124
        const float* xr = x2h_f + n * 128;
        float a0 = 0.f, a1 = 0.f, a2 = 0.f, a3 = 0.f;
#pragma unroll 4
        for (int j = 0; j < 128; j++) {
            float xv = xr[j];                             // broadcast in wave
            float4v fv = *(const float4v*)(fc1_f + j * 128 + k0);  // coalesced
            a0 += xv * fv[0]; a1 += xv * fv[1];
            a2 += xv * fv[2]; a3 += xv * fv[3];
        }
        wefft[(k0 + 0) * 512 + n] = a0;       // one-time scattered stores
        wefft[(k0 + 1) * 512 + n] = a1;
        wefft[(k0 + 2) * 512 + n] = a2;
        wefft[(k0 + 3) * 512 + n] = a3;
        return;
    }
    int tg = (blockIdx.x - 64) * 256 + tid;   // 0..511
    float s = x2hb_f[tg] + h2hb_f[tg];
    const float4v* xr = (const float4v*)(x2h_f + tg * 128);
    const float4v* bb = (const float4v*)fc1b_f;
    for (int j = 0; j < 32; j++) {
        float4v a = xr[j], b = bb[j];
        s += a[0] * b[0] + a[1] * b[1] + a[2] * b[2] + a[3] * b[3];
    }
    beff[tg] = s;
}

// ---------------------------------------------------------------------------
// K2 (1125 blocks x 256): role-split — table build plus ALL elementwise prep
// (runs concurrently in one launch; r10 had these serialized inside k1).
//  [0,256)    : bf16 tables (single rounding from f32 pipeline):
//               E_len[v][n] = sum_k len[v][k]*Weff^T[k][n]
//               E_ipd[v][n] = sum_k ipd[v][k]*Weff^T[64+k][n] + beff[n]
//  [256,512)  : x -> uchar2 t-major xc[t][b]
//  [512,1125) : bf16 conversions Wh, fc2; fc2b copy
// ---------------------------------------------------------------------------
__launch_bounds__(256)
__global__ void k2_kernel(const float* __restrict__ wefft, const float* __restrict__ beff,
                          const float* __restrict__ len_f, const float* __restrict__ ipd_f,
                          const int* __restrict__ xi, unsigned char* __restrict__ xc,
                          const float* __restrict__ h2h_f, const float* __restrict__ fc2_f,
                          const float* __restrict__ fc2b_f,
                          unsigned short* __restrict__ elen, unsigned short* __restrict__ eipd,
                          unsigned short* __restrict__ o_wh, unsigned short* __restrict__ o_fc2,
                          float* __restrict__ o_fc2b) {
    const int tid = threadIdx.x;
    if (blockIdx.x < 256) {
        int grp = blockIdx.x * 256 + tid;      // 0..65535
        int tab = grp >> 15;                   // 0: len, 1: ipd
        int g2  = grp & 32767;
        int v   = g2 >> 7;
        int n0  = (g2 & 127) * 4;
        const float* emb = (tab ? ipd_f : len_f) + v * 64;
        const float* wt  = wefft + tab * 64 * 512 + n0;
        float a0 = 0.f, a1 = 0.f, a2 = 0.f, a3 = 0.f;
#pragma unroll 8
        for (int k = 0; k < 64; k++) {
            float e = emb[k];
            float4v w = *(const float4v*)(wt + k * 512);
            a0 += e * w[0]; a1 += e * w[1]; a2 += e * w[2]; a3 += e * w[3];
        }
        if (tab) {
            float4v b4 = *(const float4v*)&beff[n0];
            a0 += b4[0]; a1 += b4[1]; a2 += b4[2]; a3 += b4[3];
        }
        us4 o = { f2bf(a0), f2bf(a1), f2bf(a2), f2bf(a3) };
        unsigned short* dst = tab ? eipd : elen;
        *(us4*)&dst[v * 512 + n0] = o;
        return;
    }
    if (blockIdx.x < 512) {
        __shared__ int is64;
        if (tid == 0) {
            int nz = 0;
            for (int j = 1; j < 64; j += 2) nz |= xi[j];
            is64 = (nz == 0) ? 1 : 0;
        }
        __syncthreads();
        const int n = B_SZ * T_SZ * 2;
        const int i64 = is64;
        for (int i = (blockIdx.x - 256) * 256 + tid; i < n; i += 256 * 256) {
            int v = i64 ? xi[2 * i] : xi[i];
            v = v < 0 ? 0 : (v > 255 ? 255 : v);
            int b = i >> 8, r = i & 255, t = r >> 1, c = r & 1;
            xc[t * 2048 + b * 2 + c] = (unsigned char)v;
        }
        return;
    }
    const int N2 = 262144, N3 = 51200, N5 = 100;
    const int total = N2 + N3 + N5;
    for (int i = (blockIdx.x - 512) * 256 + tid; i < total; i += 613 * 256) {
        int j = i;
        if (j < N2) { o_wh[j] = f2bf(h2h_f[j]); continue; }
        j -= N2;
        if (j < N3) { o_fc2[j] = f2bf(fc2_f[j]); continue; }
        j -= N3;
        o_fc2b[j] = fc2b_f[j];
    }
}

// ---------------------------------------------------------------------------
// RNN v7 (UNCHANGED from r10, proven 315 us / absmax 0.00195): v3 structure,
// bf16 tables, r9 software pipeline (idxP 1 step ahead, add at consume site),
// uchar2 t-major idx (1 broadcast line/wave/step).
// Register architecture note (r1/r10 lesson): 2 waves/SIMD budget = 128 VGPR
// + 192 AGPR; whr (192, MFMA-A) fits AGPR exactly — whr[4][16] (256) would
// overflow into VGPRs and spill. Do not attempt full-Wh-in-regs at 8 waves.
// ---------------------------------------------------------------------------
__launch_bounds__(512, 2)
__global__ void rnn_kernel(const unsigned short* __restrict__ w_wh,
                           const unsigned char* __restrict__ w_xc,
                           const unsigned short* __restrict__ w_elen,
                           const unsigned short* __restrict__ w_eipd,
                           const unsigned short* __restrict__ w_fc2,
                           const float* __restrict__ w_fc2b,
                           float* __restrict__ out) {
    extern __shared__ unsigned short sm2[];
    unsigned short* sA = sm2;            // Wh k 384..511: 65536 ushorts (128 KB)
    unsigned short* sH = sm2 + 65536;    // h dbuf: 2 x 8192 ushorts (32 KB)

    const int tid  = threadIdx.x;
    const int wv   = tid >> 6;           // 0..7
    const int ln   = tid & 63;
    const int mcol = ln & 15;            // batch col within block
    const int q    = ln >> 4;
    const int g    = blockIdx.x;
    const int b0   = g * 16;
    const int n0   = wv * 64;            // wave owns hidden rows n0..n0+63

    // ---- stage Wh kt 12..15 into LDS (swizzled) ----
    for (int it = 0; it < 16; it++) {
        int chunk = it * 512 + tid;          // 0..8191
        int r = chunk >> 4, c = chunk & 15;
        uint4 v = *(const uint4*)(w_wh + r * 512 + 384 + c * 8);
        *(uint4*)&sA[r * 128 + ((c ^ (r & 15)) & 15) * 8] = v;
    }
    // ---- zero h buffer 0 ----
    {
        uint4 z = {0, 0, 0, 0};
        *(uint4*)&sH[tid * 8] = z;
        *(uint4*)&sH[(512 + tid) * 8] = z;
    }
    // ---- Wh kt 0..11 into registers: 48 frags = 192 regs (AGPR) ----
    short8 whr[4][12];
#pragma unroll
    for (int nt = 0; nt < 4; nt++)
#pragma unroll
        for (int kt = 0; kt < 12; kt++)
            whr[nt][kt] = *(const short8*)(w_wh + (n0 + nt * 16 + mcol) * 512 + kt * 32 + q * 8);

    // ---- strength-reduced swizzle offsets (ushort units) ----
    const int qlo = (q ^ (mcol & 3)) * 8;
    int ej[4];
#pragma unroll
    for (int j = 0; j < 4; j++)
        ej[j] = ((j * 4) ^ (mcol & 12)) * 8;
    const int base_b = mcol * 512 + qlo;          // h-read base
    const int fbase  = (n0 + mcol) * 128 + qlo;   // sA-read base
    int hw_off[4];
#pragma unroll
    for (int nt = 0; nt < 4; nt++) {
        int n = n0 + nt * 16 + q * 4;
        hw_off[nt] = mcol * 512 + (((n >> 3) ^ mcol) & 63) * 8 + (n & 7);
    }

    // ---- gather pipeline prologue (bf16 tables, packed uchar2 idx) ----
    const int xb2  = (b0 + mcol) * 2;     // byte offset within a t-slice
    const int ecol = n0 + q * 4;
    us4 tq[4], ti[4];
    {
        unsigned int i0 = *(const unsigned short*)&w_xc[xb2];          // x[t=0]
        const unsigned short* eL = w_elen + (i0 & 255u) * 512 + ecol;
        const unsigned short* eI = w_eipd + (i0 >> 8) * 512 + ecol;
#pragma unroll
        for (int nt = 0; nt < 4; nt++) {
            tq[nt] = *(const us4*)(eL + nt * 16);
            ti[nt] = *(const us4*)(eI + nt * 16);
        }
    }
    unsigned int idxP = *(const unsigned short*)&w_xc[2048 + xb2];     // x[t=1]

    __syncthreads();

    for (int t = 0; t < T_SZ; t++) {
        const unsigned short* hRd = sH + ((t & 1) << 13);
        unsigned short* hWr = sH + (((t + 1) & 1) << 13);

        // ---- acc init: bf16->f32 + add at CONSUME site (loads landed) ----
        float4v acc[4];
#pragma unroll
        for (int nt = 0; nt < 4; nt++) {
            acc[nt][0] = bf2f(tq[nt][0]) + bf2f(ti[nt][0]);
            acc[nt][1] = bf2f(tq[nt][1]) + bf2f(ti[nt][1]);
            acc[nt][2] = bf2f(tq[nt][2]) + bf2f(ti[nt][2]);
            acc[nt][3] = bf2f(tq[nt][3]) + bf2f(ti[nt][3]);
        }
        // ---- issue next-step table loads (idxP resident -> no chain) ----
        if (t + 1 < T_SZ) {
            const unsigned short* eL = w_elen + (idxP & 255u) * 512 + ecol;
            const unsigned short* eI = w_eipd + (idxP >> 8) * 512 + ecol;
#pragma unroll
            for (int nt = 0; nt < 4; nt++) {
                tq[nt] = *(const us4*)(eL + nt * 16);
                ti[nt] = *(const us4*)(eI + nt * 16);
            }
            if (t + 2 < T_SZ)
                idxP = *(const unsigned short*)&w_xc[(t + 2) * 2048 + xb2];
        }

        // ---- Wh MFMAs: kt 0..11 from regs ----
#pragma unroll
        for (int kt = 0; kt < 12; kt++) {
            short8 bh = *(const short8*)&hRd[base_b + ej[kt & 3] + (kt >> 2) * 128];
#pragma unroll
            for (int nt = 0; nt < 4; nt++)
                acc[nt] = mfma16(whr[nt][kt], bh, acc[nt]);
        }
        // ---- kt 12..15 from LDS ----
#pragma unroll
        for (int j = 0; j < 4; j++) {
            short8 bh = *(const short8*)&hRd[base_b + ej[j] + 384];
#pragma unroll
            for (int nt = 0; nt < 4; nt++) {
                short8 fa = *(const short8*)&sA[fbase + nt * 2048 + ej[j]];
                acc[nt] = mfma16(fa, bh, acc[nt]);
            }
        }

        // ---- fast tanh -> bf16, write h(t+1) into other buffer ----
#pragma unroll
        for (int nt = 0; nt < 4; nt++) {
            unsigned short o[4];
#pragma unroll
            for (int r = 0; r < 4; r++) {
                float e  = __expf(2.0f * acc[nt][r]);
                float th = 1.0f - 2.0f * __builtin_amdgcn_rcpf(e + 1.0f);
                o[r] = f2bf(th);
            }
            us4 v4 = { o[0], o[1], o[2], o[3] };
            *(us4*)&hWr[hw_off[nt]] = v4;
        }
        __syncthreads();   // h(t+1) visible to all waves before next step
    }

    // final h is in buffer 0 (T_SZ even)
    unsigned short* hF = sH;

    // ---- fc2 epilogue: waves 0..6 cover 112 >= 100 labels ----
    if (wv < 7) {
        int lA = wv * 16 + mcol; if (lA > 99) lA = 99;
        float4v a2 = {0.f, 0.f, 0.f, 0.f};
#pragma unroll
        for (int kt = 0; kt < 16; kt++) {
            short8 fa = *(const short8*)(w_fc2 + lA * 512 + kt * 32 + q * 8);
            short8 bh = *(const short8*)&hF[base_b + ej[kt & 3] + (kt >> 2) * 128];
            a2 = mfma16(fa, bh, a2);
        }
#pragma unroll
        for (int r = 0; r < 4; r++) {
            int l = wv * 16 + q * 4 + r;
            if (l < 100) out[(b0 + mcol) * 100 + l] = a2[r] + w_fc2b[l];
        }
    }
}

extern "C" void kernel_launch(void* const* d_in, const int* in_sizes, int n_in,
                              void* d_out, int out_size, void* d_ws, size_t ws_size,
                              hipStream_t stream) {
    unsigned char* base = (unsigned char*)d_ws;
    if (ws_size < (size_t)WS_NEED) {
        void* p = nullptr;
        hipGetSymbolAddress(&p, HIP_SYMBOL(g_blob));
        base = (unsigned char*)p;
    }
    unsigned char*  w_xc    = base + OFF_XC;
    unsigned short* w_wh    = (unsigned short*)(base + OFF_WH);
    unsigned short* w_fc2   = (unsigned short*)(base + OFF_FC2);
    float*          w_fc2b  = (float*)(base + OFF_FC2B);
    float*          w_wefft = (float*)(base + OFF_WEFFT);
    float*          w_beff  = (float*)(base + OFF_BEFF);
    unsigned short* w_elen  = (unsigned short*)(base + OFF_ELEN);
    unsigned short* w_eipd  = (unsigned short*)(base + OFF_EIPD);

    static bool attr_set = false;
    if (!attr_set) {
        hipFuncSetAttribute((const void*)rnn_kernel,
                            hipFuncAttributeMaxDynamicSharedMemorySize, 163840);
        attr_set = true;
    }

    k1_kernel<<<66, 256, 0, stream>>>(
        (const float*)d_in[3], (const float*)d_in[4],
        (const float*)d_in[5], (const float*)d_in[6], (const float*)d_in[8],
        w_wefft, w_beff);
    k2_kernel<<<1125, 256, 0, stream>>>(
        w_wefft, w_beff,
        (const float*)d_in[1], (const float*)d_in[2],
        (const int*)d_in[0], w_xc,
        (const float*)d_in[7], (const float*)d_in[9], (const float*)d_in[10],
        w_elen, w_eipd, w_wh, w_fc2, w_fc2b);
    rnn_kernel<<<64, 512, 163840, stream>>>(
        w_wh, w_xc, w_elen, w_eipd, w_fc2, w_fc2b, (float*)d_out);
}